// Round 8
// baseline (287.543 us; speedup 1.0000x reference)
//
#include <hip/hip_runtime.h>

typedef unsigned int u32;
typedef unsigned long long u64;

#define C_DIM 256
#define HW 1024
#define N_TOT 16384
#define K_DIM 8192
#define ZQ_SIZE 4194304
#define LOSS_OFF ZQ_SIZE
#define IDX_OFF (ZQ_SIZE + 1)

#define KRANGE 2048
#define MARGIN 2.0f
#define CAP 524288u
#define LCAP 8192u

// workspace offsets (floats)
#define WS_ENORM 0          // 8192 (stores ||e||^2 + 1024)
#define WS_CNT 8192         // 1 u32
#define WS_PACKED 16384     // 16384 u64 = 32768 f
#define WS_LIST 131072      // CAP uint2 = 1048576 f
#define WS_ZT32 1179648     // 4194304
#define WS_ZTB16 5373952    // 2097152
#define WS_EB16 7471104     // 1048576 -> ends 8519680 f = 34.1 MB

typedef __attribute__((ext_vector_type(4))) float f32x4;
typedef __attribute__((ext_vector_type(8))) __bf16 bf16x8;
typedef __attribute__((ext_vector_type(8))) unsigned short u16x8;

__device__ __forceinline__ void gld_lds16(const void* g, void* l) {
    __builtin_amdgcn_global_load_lds(
        (const __attribute__((address_space(1))) u32*)g,
        (__attribute__((address_space(3))) u32*)l, 16, 0, 0);
}

__device__ __forceinline__ unsigned short f2bf(float f) {
    u32 u = __float_as_uint(f);
    u32 r = (u + 0x7FFFu + ((u >> 16) & 1u)) >> 16;   // RNE
    return (unsigned short)r;
}

// ---------------- fused prep: e -> bf16 + (||e||^2+1024); z -> transpose fp32+bf16 ----------------
__global__ __launch_bounds__(256) void k_prep(const float* __restrict__ z,
                                              const float* __restrict__ e,
                                              float* __restrict__ zt32,
                                              unsigned short* __restrict__ ztb,
                                              unsigned short* __restrict__ eb,
                                              float* __restrict__ enorm1) {
    int bid = blockIdx.x;
    int t = threadIdx.x;
    // ---- part 1: codebook rows 4*bid .. 4*bid+3 ----
    {
        int w = t >> 6, l = t & 63;
        int row = bid * 4 + w;
        const float4 v = *reinterpret_cast<const float4*>(e + (size_t)row * C_DIM + l * 4);
        float s = v.x * v.x + v.y * v.y + v.z * v.z + v.w * v.w;
        #pragma unroll
        for (int off = 32; off; off >>= 1) s += __shfl_xor(s, off, 64);
        if (l == 0) enorm1[row] = s + 1024.0f;
        ushort4 h;
        h.x = f2bf(v.x); h.y = f2bf(v.y); h.z = f2bf(v.z); h.w = f2bf(v.w);
        *reinterpret_cast<ushort4*>(eb + (size_t)row * C_DIM + l * 4) = h;
    }
    // ---- part 2: z transpose tile ----
    int b = bid >> 7;
    int hwt = (bid >> 3) & 15;
    int ct = bid & 7;
    __shared__ float tile[32][65];
    #pragma unroll
    for (int p = 0; p < 8; ++p) {
        int cl = p * 4 + (t >> 6), hl = t & 63;
        tile[cl][hl] = z[((size_t)b << 18) + ((size_t)(ct * 32 + cl) << 10) + hwt * 64 + hl];
    }
    __syncthreads();
    int hl = t & 63, cg = t >> 6;
    int n = (b << 10) + hwt * 64 + hl;
    float v[8];
    #pragma unroll
    for (int j = 0; j < 8; ++j) v[j] = tile[cg * 8 + j][hl];
    size_t base = (size_t)n * C_DIM + ct * 32 + cg * 8;
    *reinterpret_cast<float4*>(zt32 + base) = make_float4(v[0], v[1], v[2], v[3]);
    *reinterpret_cast<float4*>(zt32 + base + 4) = make_float4(v[4], v[5], v[6], v[7]);
    u16x8 h;
    #pragma unroll
    for (int j = 0; j < 8; ++j) h[j] = f2bf(v[j]);
    *reinterpret_cast<u16x8*>(ztb + base) = h;
}

// ---------------- single-pass MFMA screen: A in LDS, B global->reg ring-4 distance-3, pinned ----------------
__global__ __launch_bounds__(256, 2) void k_screen(const unsigned short* __restrict__ zt,
                                                   const unsigned short* __restrict__ et,
                                                   const float* __restrict__ enorm1,
                                                   u32* __restrict__ cnt,
                                                   uint2* __restrict__ list) {
    __shared__ __align__(16) char lds[67088];   // A 64KB + emission scratch tail
    char* Ab = lds;

    int logical = (blockIdx.x & 7) * 64 + (blockIdx.x >> 3);   // bijective, XCD-grouped
    const int ks = logical >> 7;
    const int rowtile = logical & 127;
    const int n0 = rowtile * 128;
    const int kbase = ks * KRANGE;

    const int tid = threadIdx.x;
    const int l = tid & 63, w = tid >> 6;
    const int wr = w >> 1, wc = w & 1;
    const int ll = l & 15, lh = l >> 4;

    // ---- stage A once: 128 rows x 256 c bf16 (inverse-swizzled source, linear dest) ----
    #pragma unroll
    for (int j = 0; j < 16; ++j) {
        int Y = (w * 16 + j) * 1024 + l * 16;      // byte
        int row = Y >> 9;
        int slot = (Y >> 4) & 31;
        const char* src = (const char*)zt + (((size_t)(n0 + row)) << 9) + ((slot ^ (row & 7)) << 4);
        gld_lds16(src, Ab + (w * 16 + j) * 1024);
    }

    // af addressing (row part constant)
    int aoff[4], rxA[4];
    #pragma unroll
    for (int mf = 0; mf < 4; ++mf) {
        int row = wr * 64 + mf * 16 + ll;
        aoff[mf] = row * 512;
        rxA[mf] = row & 7;
    }

    // B per-lane base: fragment (it,cs,kf) at ebB + it*65536 + kf*8192 + cs*64
    const char* ebB = (const char*)et + (((size_t)(kbase + wc * 64 + ll)) << 9) + lh * 16;

    f32x4 acc[4][4];
    #pragma unroll
    for (int a = 0; a < 4; ++a)
        #pragma unroll
        for (int b = 0; b < 4; ++b) acc[a][b] = (f32x4){0.f, 0.f, 0.f, 0.f};
    float m1[16], m2[16];
    #pragma unroll
    for (int s = 0; s < 16; ++s) { m1[s] = 3.4e38f; m2[s] = 3.4e38f; }

    // ring-4 register pipeline, prefetch distance 3 (all indices compile-time)
    bf16x8 bb[4][4];
    #pragma unroll
    for (int j = 0; j < 3; ++j)
        #pragma unroll
        for (int kf = 0; kf < 4; ++kf)
            bb[j][kf] = *reinterpret_cast<const bf16x8*>(ebB + j * 64 + kf * 8192);

    __syncthreads();   // A tile ready (drains prologue B too — once, acceptable)

    for (int it = 0; it < 16; ++it) {
        float en[4];
        #pragma unroll
        for (int kf = 0; kf < 4; ++kf)
            en[kf] = enorm1[kbase + it * 128 + wc * 64 + kf * 16 + ll];

        #pragma unroll
        for (int cs = 0; cs < 8; ++cs) {
            // issue prefetch for step (it,cs+3) into slot (cs+3)&3
            {
                const int pit = it + ((cs + 3) >> 3);            // compile-time carry
                const int pcs = (cs + 3) & 7;
                const size_t poff = (pit > 15) ? 0 : (((size_t)pit << 16) + pcs * 64);
                #pragma unroll
                for (int kf = 0; kf < 4; ++kf)
                    bb[(cs + 3) & 3][kf] =
                        *reinterpret_cast<const bf16x8*>(ebB + poff + kf * 8192);
            }
            // pin: the loads above must ISSUE before this step's compute (no sinking)
            __builtin_amdgcn_sched_barrier(0);
            bf16x8 af[4];
            #pragma unroll
            for (int mf = 0; mf < 4; ++mf)
                af[mf] = *reinterpret_cast<const bf16x8*>(
                    Ab + aoff[mf] + (((cs * 4 + lh) ^ rxA[mf]) << 4));
            __builtin_amdgcn_s_setprio(1);
            #pragma unroll
            for (int mf = 0; mf < 4; ++mf)
                #pragma unroll
                for (int kf = 0; kf < 4; ++kf)
                    acc[mf][kf] = __builtin_amdgcn_mfma_f32_16x16x32_bf16(
                        af[mf], bb[cs & 3][kf], acc[mf][kf], 0, 0, 0);
            __builtin_amdgcn_s_setprio(0);
        }

        // epilogue: packed (d,k) top-2 update; d = en' - 2*dot
        #pragma unroll
        for (int kf = 0; kf < 4; ++kf) {
            const u32 kcol = (u32)(kbase + it * 128 + wc * 64 + kf * 16 + ll);
            #pragma unroll
            for (int mf = 0; mf < 4; ++mf) {
                #pragma unroll
                for (int r = 0; r < 4; ++r) {
                    float d = fmaf(-2.0f, acc[mf][kf][r], en[kf]);
                    float df = __uint_as_float((__float_as_uint(d) & 0xFFFFE000u) | kcol);
                    const int s2 = mf * 4 + r;
                    float t = fmaxf(m1[s2], df);
                    m2[s2] = fminf(m2[s2], t);
                    m1[s2] = fminf(m1[s2], df);
                    acc[mf][kf][r] = 0.0f;
                }
            }
        }
    }

    // ---- row-split min via butterfly on a COPY (per-thread m1/m2 preserved) ----
    float rowm[16];
    #pragma unroll
    for (int s = 0; s < 16; ++s) rowm[s] = m1[s];
    #pragma unroll
    for (int m = 1; m <= 8; m <<= 1)
        #pragma unroll
        for (int s = 0; s < 16; ++s)
            rowm[s] = fminf(rowm[s], __shfl_xor(rowm[s], m, 64));

    // LDS scratch (tail region; cbuf reuses A after barriers)
    float* LDSrm = (float*)(lds + 65536);    // [128][2]
    float* LDSrmF = (float*)(lds + 66560);   // [128]
    u32* ccnt = (u32*)(lds + 67072);
    u32* gbase = (u32*)(lds + 67076);
    uint2* cbuf = (uint2*)Ab;                // 8192 entries

    if (ll == 0) {
        #pragma unroll
        for (int s = 0; s < 16; ++s) {
            int row_local = wr * 64 + (s >> 2) * 16 + lh * 4 + (s & 3);
            LDSrm[row_local * 2 + wc] = rowm[s];
        }
    }
    if (tid == 0) *ccnt = 0;
    __syncthreads();
    if (tid < 128)
        LDSrmF[tid] = fminf(LDSrm[tid * 2], LDSrm[tid * 2 + 1]);
    __syncthreads();

    // ---- emission (per-thread bests; block-compacted) ----
    #pragma unroll
    for (int s = 0; s < 16; ++s) {
        int row_local = wr * 64 + (s >> 2) * 16 + lh * 4 + (s & 3);
        float rm = __uint_as_float(__float_as_uint(LDSrmF[row_local]) & 0xFFFFE000u);
        float d1 = __uint_as_float(__float_as_uint(m1[s]) & 0xFFFFE000u);
        if (d1 <= rm + MARGIN) {
            u32 pos = atomicAdd(ccnt, 1u);
            uint2 ent = make_uint2((u32)(n0 + row_local), __float_as_uint(m1[s]) & 8191u);
            if (pos < LCAP) cbuf[pos] = ent;
            else { u32 gp = atomicAdd(cnt, 1u); if (gp < CAP) list[gp] = ent; }
        }
        float d2 = __uint_as_float(__float_as_uint(m2[s]) & 0xFFFFE000u);
        if (d2 <= rm + MARGIN) {
            // rare: a 3rd candidate may hide in this thread-slot's 64-k subset -> emit all
            for (int it2 = 0; it2 < 16; ++it2) {
                #pragma unroll
                for (int kf = 0; kf < 4; ++kf) {
                    u32 k = (u32)(kbase + it2 * 128 + wc * 64 + kf * 16 + ll);
                    u32 pos = atomicAdd(ccnt, 1u);
                    uint2 ent = make_uint2((u32)(n0 + row_local), k);
                    if (pos < LCAP) cbuf[pos] = ent;
                    else { u32 gp = atomicAdd(cnt, 1u); if (gp < CAP) list[gp] = ent; }
                }
            }
        }
    }
    __syncthreads();
    if (tid == 0) {
        u32 total = *ccnt; if (total > LCAP) total = LCAP;
        *gbase = atomicAdd(cnt, total);
    }
    __syncthreads();
    u32 total = *ccnt; if (total > LCAP) total = LCAP;
    u32 gb = *gbase;
    for (u32 i = tid; i < total; i += 256) {
        u32 gp = gb + i;
        if (gp < CAP) list[gp] = cbuf[i];
    }
}

// ---------------- exact fp32 recheck of candidates ----------------
__global__ __launch_bounds__(256) void k_exact(const float* __restrict__ zt32,
                                               const float* __restrict__ e,
                                               const float* __restrict__ enorm1,
                                               const u32* __restrict__ cnt,
                                               const uint2* __restrict__ list,
                                               u64* __restrict__ packed) {
    const int nw = gridDim.x * 4;
    const int wid = blockIdx.x * 4 + (threadIdx.x >> 6);
    const int l = threadIdx.x & 63;
    u32 total = *cnt;
    if (total > CAP) total = CAP;
    for (u32 i = wid; i < total; i += nw) {
        uint2 c = list[i];
        const float4 zv = *reinterpret_cast<const float4*>(zt32 + (size_t)c.x * C_DIM + l * 4);
        const float4 ev = *reinterpret_cast<const float4*>(e + (size_t)c.y * C_DIM + l * 4);
        float s = zv.x * ev.x + zv.y * ev.y + zv.z * ev.z + zv.w * ev.w;
        #pragma unroll
        for (int off = 32; off; off >>= 1) s += __shfl_xor(s, off, 64);
        if (l == 0) {
            float d = fmaf(-2.0f, s, enorm1[c.y]);   // +1024 shift uniform: order preserved
            u32 ub = __float_as_uint(d);
            ub = (ub & 0x80000000u) ? ~ub : (ub | 0x80000000u);
            u64 key = ((u64)ub << 32) | (u64)c.y;
            atomicMin(packed + c.x, key);
        }
    }
}

// ---------------- gather z_q + fused loss (atomicAdd) + index finalize ----------------
#define GBLOCKS 2048
__global__ __launch_bounds__(256) void k_gather(const float* __restrict__ z,
                                                const float* __restrict__ e,
                                                const u64* __restrict__ packed,
                                                float* __restrict__ zq,
                                                float* __restrict__ out_loss,
                                                float* __restrict__ out_idx) {
    float s = 0.0f;
    for (int i = blockIdx.x * 256 + threadIdx.x; i < ZQ_SIZE; i += GBLOCKS * 256) {
        int bb = i >> 18;
        int c = (i >> 10) & 255;
        int hw = i & 1023;
        int n = (bb << 10) | hw;
        u32 kk = (u32)(packed[n] & 0xFFFFFFFFull);
        if (kk > 8191u) kk = 0u;   // safety net: visible wrong answer instead of GPU fault
        float q = e[(size_t)kk * C_DIM + c];
        float zv = z[i];
        zq[i] = q;
        if (c == 0) out_idx[n] = (float)kk;
        float d = q - zv;
        s = fmaf(d, d, s);
    }
    #pragma unroll
    for (int off = 32; off; off >>= 1) s += __shfl_xor(s, off, 64);
    __shared__ float wsum[4];
    int lane = threadIdx.x & 63, w = threadIdx.x >> 6;
    if (lane == 0) wsum[w] = s;
    __syncthreads();
    if (threadIdx.x == 0)
        atomicAdd(out_loss, (wsum[0] + wsum[1] + wsum[2] + wsum[3]) * (1.25f / (float)ZQ_SIZE));
}

extern "C" void kernel_launch(void* const* d_in, const int* in_sizes, int n_in,
                              void* d_out, int out_size, void* d_ws, size_t ws_size,
                              hipStream_t stream) {
    const float* z = (const float*)d_in[0];
    const float* e = (const float*)d_in[1];
    float* out = (float*)d_out;
    float* ws = (float*)d_ws;

    float* enorm1 = ws + WS_ENORM;
    u32* cnt = (u32*)(ws + WS_CNT);
    u64* packed = (u64*)(ws + WS_PACKED);
    uint2* list = (uint2*)(ws + WS_LIST);
    float* zt32 = ws + WS_ZT32;
    unsigned short* ztb = (unsigned short*)(ws + WS_ZTB16);
    unsigned short* eb = (unsigned short*)(ws + WS_EB16);

    hipMemsetAsync(cnt, 0, sizeof(u32), stream);
    hipMemsetAsync(packed, 0xFF, (size_t)N_TOT * sizeof(u64), stream);
    hipMemsetAsync(out + LOSS_OFF, 0, sizeof(float), stream);

    k_prep<<<dim3(2048), dim3(256), 0, stream>>>(z, e, zt32, ztb, eb, enorm1);
    k_screen<<<dim3(512), dim3(256), 0, stream>>>(ztb, eb, enorm1, cnt, list);
    k_exact<<<dim3(512), dim3(256), 0, stream>>>(zt32, e, enorm1, cnt, list, packed);
    k_gather<<<dim3(GBLOCKS), dim3(256), 0, stream>>>(z, e, packed, out, out + LOSS_OFF, out + IDX_OFF);
}

// Round 9
// 275.088 us; speedup vs baseline: 1.0453x; 1.0453x over previous
//
#include <hip/hip_runtime.h>

typedef unsigned int u32;
typedef unsigned long long u64;

#define C_DIM 256
#define HW 1024
#define N_TOT 16384
#define K_DIM 8192
#define ZQ_SIZE 4194304
#define LOSS_OFF ZQ_SIZE
#define IDX_OFF (ZQ_SIZE + 1)

#define KRANGE 2048
#define MARGIN 2.0f
#define CAP 524288u
#define LCAP 8192u

// workspace offsets (floats)
#define WS_ENORM 0          // 8192 (stores ||e||^2 + 1024)
#define WS_CNT 8192         // 1 u32
#define WS_PACKED 16384     // 16384 u64 = 32768 f
#define WS_FIDX 49152       // 16384
#define WS_LPART 65536      // 2048
#define WS_LIST 131072      // CAP uint2 = 1048576 f
#define WS_ZT32 1179648     // 4194304
#define WS_ZTB16 5373952    // 2097152
#define WS_EB16 7471104     // 1048576 -> ends 8519680 f = 34.1 MB

typedef __attribute__((ext_vector_type(4))) float f32x4;
typedef __attribute__((ext_vector_type(8))) __bf16 bf16x8;
typedef __attribute__((ext_vector_type(8))) unsigned short u16x8;

__device__ __forceinline__ void gld_lds16(const void* g, void* l) {
    __builtin_amdgcn_global_load_lds(
        (const __attribute__((address_space(1))) u32*)g,
        (__attribute__((address_space(3))) u32*)l, 16, 0, 0);
}

// async 16B global->VGPR load the compiler cannot track (manual vmcnt discipline)
__device__ __forceinline__ bf16x8 gload16(u64 addr) {
    bf16x8 r;
    asm volatile("global_load_dwordx4 %0, %1, off" : "=v"(r) : "v"(addr));
    return r;
}

__device__ __forceinline__ unsigned short f2bf(float f) {
    u32 u = __float_as_uint(f);
    u32 r = (u + 0x7FFFu + ((u >> 16) & 1u)) >> 16;   // RNE
    return (unsigned short)r;
}

// ---------------- prep e: bf16 codebook + (||e||^2 + 1024) ----------------
__global__ __launch_bounds__(256) void k_prep_e(const float* __restrict__ e,
                                                unsigned short* __restrict__ eb,
                                                float* __restrict__ enorm1) {
    int w = threadIdx.x >> 6, l = threadIdx.x & 63;
    int row = blockIdx.x * 4 + w;
    const float4 v = *reinterpret_cast<const float4*>(e + (size_t)row * C_DIM + l * 4);
    float s = v.x * v.x + v.y * v.y + v.z * v.z + v.w * v.w;
    #pragma unroll
    for (int off = 32; off; off >>= 1) s += __shfl_xor(s, off, 64);
    if (l == 0) enorm1[row] = s + 1024.0f;
    ushort4 h;
    h.x = f2bf(v.x); h.y = f2bf(v.y); h.z = f2bf(v.z); h.w = f2bf(v.w);
    *reinterpret_cast<ushort4*>(eb + (size_t)row * C_DIM + l * 4) = h;
}

// ---------------- prep z: transpose to [n][c], fp32 + bf16 ----------------
__global__ __launch_bounds__(256) void k_prep_z(const float* __restrict__ z,
                                                float* __restrict__ zt32,
                                                unsigned short* __restrict__ ztb) {
    int bid = blockIdx.x;
    int b = bid >> 7;
    int hwt = (bid >> 3) & 15;
    int ct = bid & 7;
    int t = threadIdx.x;
    __shared__ float tile[32][65];
    #pragma unroll
    for (int p = 0; p < 8; ++p) {
        int cl = p * 4 + (t >> 6), hl = t & 63;
        tile[cl][hl] = z[((size_t)b << 18) + ((size_t)(ct * 32 + cl) << 10) + hwt * 64 + hl];
    }
    __syncthreads();
    int hl = t & 63, cg = t >> 6;
    int n = (b << 10) + hwt * 64 + hl;
    float v[8];
    #pragma unroll
    for (int j = 0; j < 8; ++j) v[j] = tile[cg * 8 + j][hl];
    size_t base = (size_t)n * C_DIM + ct * 32 + cg * 8;
    *reinterpret_cast<float4*>(zt32 + base) = make_float4(v[0], v[1], v[2], v[3]);
    *reinterpret_cast<float4*>(zt32 + base + 4) = make_float4(v[4], v[5], v[6], v[7]);
    u16x8 h;
    #pragma unroll
    for (int j = 0; j < 8; ++j) h[j] = f2bf(v[j]);
    *reinterpret_cast<u16x8*>(ztb + base) = h;
}

// ---------------- single-pass MFMA screen: A+enorm in LDS, B inline-asm reg pipeline ----------------
__global__ __launch_bounds__(256, 2) void k_screen(const unsigned short* __restrict__ zt,
                                                   const unsigned short* __restrict__ et,
                                                   const float* __restrict__ enorm1,
                                                   u32* __restrict__ cnt,
                                                   uint2* __restrict__ list) {
    __shared__ __align__(16) char lds[75280];   // A 64KB + enorm 8KB + scratch tail
    char* Ab = lds;
    float* eldsF = (float*)(lds + 65536);

    int logical = (blockIdx.x & 7) * 64 + (blockIdx.x >> 3);   // bijective, XCD-grouped
    const int ks = logical >> 7;
    const int rowtile = logical & 127;
    const int n0 = rowtile * 128;
    const int kbase = ks * KRANGE;

    const int tid = threadIdx.x;
    const int l = tid & 63, w = tid >> 6;
    const int wr = w >> 1, wc = w & 1;
    const int ll = l & 15, lh = l >> 4;

    // ---- stage A once: 128 rows x 256 c bf16 (inverse-swizzled source, linear dest) ----
    #pragma unroll
    for (int j = 0; j < 16; ++j) {
        int Y = (w * 16 + j) * 1024 + l * 16;      // byte
        int row = Y >> 9;
        int slot = (Y >> 4) & 31;
        const char* src = (const char*)zt + (((size_t)(n0 + row)) << 9) + ((slot ^ (row & 7)) << 4);
        gld_lds16(src, Ab + (w * 16 + j) * 1024);
    }
    // ---- stage enorm slice (2048 f = 8KB) so the K-loop has ZERO compiler-visible VMEM ----
    #pragma unroll
    for (int r = 0; r < 2; ++r) {
        const char* src = (const char*)(enorm1 + kbase) + r * 4096 + w * 1024 + l * 16;
        gld_lds16(src, lds + 65536 + r * 4096 + w * 1024);
    }

    // af addressing (row part constant)
    int aoff[4], rxA[4];
    #pragma unroll
    for (int mf = 0; mf < 4; ++mf) {
        int row = wr * 64 + mf * 16 + ll;
        aoff[mf] = row * 512;
        rxA[mf] = row & 7;
    }

    // B per-lane base: fragment (it,cs,kf) at ebB + it*65536 + kf*8192 + cs*64
    const u64 ebB = (u64)((const char*)et + (((size_t)(kbase + wc * 64 + ll)) << 9) + lh * 16);

    f32x4 acc[4][4];
    #pragma unroll
    for (int a = 0; a < 4; ++a)
        #pragma unroll
        for (int b = 0; b < 4; ++b) acc[a][b] = (f32x4){0.f, 0.f, 0.f, 0.f};
    float m1[16], m2[16];
    #pragma unroll
    for (int s = 0; s < 16; ++s) { m1[s] = 3.4e38f; m2[s] = 3.4e38f; }

    __syncthreads();   // A + enorm ready (drains the DMA; vmcnt==0 here)

    // ---- prologue: fill ring slots 0..2 (12 outstanding asm loads) ----
    bf16x8 bb[4][4];
    #pragma unroll
    for (int j = 0; j < 3; ++j)
        #pragma unroll
        for (int kf = 0; kf < 4; ++kf)
            bb[j][kf] = gload16(ebB + j * 64 + kf * 8192);

    for (int it = 0; it < 16; ++it) {
        #pragma unroll
        for (int cs = 0; cs < 8; ++cs) {
            // issue prefetch for step (it,cs+3) into slot (cs+3)&3  -> 16 outstanding
            {
                const int pit = it + ((cs + 3) >> 3);            // compile-time carry
                const int pcs = (cs + 3) & 7;
                const u64 poff = (pit > 15) ? 0 : (((u64)pit << 16) + (u64)(pcs * 64));
                #pragma unroll
                for (int kf = 0; kf < 4; ++kf)
                    bb[(cs + 3) & 3][kf] = gload16(ebB + poff + kf * 8192);
            }
            __builtin_amdgcn_sched_barrier(0);
            bf16x8 af[4];
            #pragma unroll
            for (int mf = 0; mf < 4; ++mf)
                af[mf] = *reinterpret_cast<const bf16x8*>(
                    Ab + aoff[mf] + (((cs * 4 + lh) ^ rxA[mf]) << 4));
            // counted wait: drain only the 4 loads needed this step (12 stay in flight)
            asm volatile("s_waitcnt vmcnt(12)" ::: "memory");
            __builtin_amdgcn_sched_barrier(0);
            __builtin_amdgcn_s_setprio(1);
            #pragma unroll
            for (int mf = 0; mf < 4; ++mf)
                #pragma unroll
                for (int kf = 0; kf < 4; ++kf)
                    acc[mf][kf] = __builtin_amdgcn_mfma_f32_16x16x32_bf16(
                        af[mf], bb[cs & 3][kf], acc[mf][kf], 0, 0, 0);
            __builtin_amdgcn_s_setprio(0);
        }

        // epilogue: packed (d,k) top-2 update; d = en' - 2*dot  (enorm from LDS: lgkmcnt only)
        float en[4];
        #pragma unroll
        for (int kf = 0; kf < 4; ++kf)
            en[kf] = eldsF[it * 128 + wc * 64 + kf * 16 + ll];
        #pragma unroll
        for (int kf = 0; kf < 4; ++kf) {
            const u32 kcol = (u32)(kbase + it * 128 + wc * 64 + kf * 16 + ll);
            #pragma unroll
            for (int mf = 0; mf < 4; ++mf) {
                #pragma unroll
                for (int r = 0; r < 4; ++r) {
                    float d = fmaf(-2.0f, acc[mf][kf][r], en[kf]);
                    float df = __uint_as_float((__float_as_uint(d) & 0xFFFFE000u) | kcol);
                    const int s2 = mf * 4 + r;
                    float t = fmaxf(m1[s2], df);
                    m2[s2] = fminf(m2[s2], t);
                    m1[s2] = fminf(m1[s2], df);
                    acc[mf][kf][r] = 0.0f;
                }
            }
        }
    }
    asm volatile("s_waitcnt vmcnt(0)" ::: "memory");   // drain tail dummy prefetches

    // ---- row-split min via butterfly on a COPY (per-thread m1/m2 preserved) ----
    float rowm[16];
    #pragma unroll
    for (int s = 0; s < 16; ++s) rowm[s] = m1[s];
    #pragma unroll
    for (int m = 1; m <= 8; m <<= 1)
        #pragma unroll
        for (int s = 0; s < 16; ++s)
            rowm[s] = fminf(rowm[s], __shfl_xor(rowm[s], m, 64));

    // LDS scratch (tail region; cbuf reuses A after barriers)
    float* LDSrm = (float*)(lds + 73728);    // [128][2]
    float* LDSrmF = (float*)(lds + 74752);   // [128]
    u32* ccnt = (u32*)(lds + 75264);
    u32* gbase = (u32*)(lds + 75268);
    uint2* cbuf = (uint2*)Ab;                // 8192 entries

    if (ll == 0) {
        #pragma unroll
        for (int s = 0; s < 16; ++s) {
            int row_local = wr * 64 + (s >> 2) * 16 + lh * 4 + (s & 3);
            LDSrm[row_local * 2 + wc] = rowm[s];
        }
    }
    if (tid == 0) *ccnt = 0;
    __syncthreads();
    if (tid < 128)
        LDSrmF[tid] = fminf(LDSrm[tid * 2], LDSrm[tid * 2 + 1]);
    __syncthreads();

    // ---- emission (per-thread bests; block-compacted) ----
    #pragma unroll
    for (int s = 0; s < 16; ++s) {
        int row_local = wr * 64 + (s >> 2) * 16 + lh * 4 + (s & 3);
        float rm = __uint_as_float(__float_as_uint(LDSrmF[row_local]) & 0xFFFFE000u);
        float d1 = __uint_as_float(__float_as_uint(m1[s]) & 0xFFFFE000u);
        if (d1 <= rm + MARGIN) {
            u32 pos = atomicAdd(ccnt, 1u);
            uint2 ent = make_uint2((u32)(n0 + row_local), __float_as_uint(m1[s]) & 8191u);
            if (pos < LCAP) cbuf[pos] = ent;
            else { u32 gp = atomicAdd(cnt, 1u); if (gp < CAP) list[gp] = ent; }
        }
        float d2 = __uint_as_float(__float_as_uint(m2[s]) & 0xFFFFE000u);
        if (d2 <= rm + MARGIN) {
            // rare: a 3rd candidate may hide in this thread-slot's 64-k subset -> emit all
            for (int it2 = 0; it2 < 16; ++it2) {
                #pragma unroll
                for (int kf = 0; kf < 4; ++kf) {
                    u32 k = (u32)(kbase + it2 * 128 + wc * 64 + kf * 16 + ll);
                    u32 pos = atomicAdd(ccnt, 1u);
                    uint2 ent = make_uint2((u32)(n0 + row_local), k);
                    if (pos < LCAP) cbuf[pos] = ent;
                    else { u32 gp = atomicAdd(cnt, 1u); if (gp < CAP) list[gp] = ent; }
                }
            }
        }
    }
    __syncthreads();
    if (tid == 0) {
        u32 total = *ccnt; if (total > LCAP) total = LCAP;
        *gbase = atomicAdd(cnt, total);
    }
    __syncthreads();
    u32 total = *ccnt; if (total > LCAP) total = LCAP;
    u32 gb = *gbase;
    for (u32 i = tid; i < total; i += 256) {
        u32 gp = gb + i;
        if (gp < CAP) list[gp] = cbuf[i];
    }
}

// ---------------- exact fp32 recheck of candidates ----------------
__global__ __launch_bounds__(256) void k_exact(const float* __restrict__ zt32,
                                               const float* __restrict__ e,
                                               const float* __restrict__ enorm1,
                                               const u32* __restrict__ cnt,
                                               const uint2* __restrict__ list,
                                               u64* __restrict__ packed) {
    const int nw = gridDim.x * 4;
    const int wid = blockIdx.x * 4 + (threadIdx.x >> 6);
    const int l = threadIdx.x & 63;
    u32 total = *cnt;
    if (total > CAP) total = CAP;
    for (u32 i = wid; i < total; i += nw) {
        uint2 c = list[i];
        const float4 zv = *reinterpret_cast<const float4*>(zt32 + (size_t)c.x * C_DIM + l * 4);
        const float4 ev = *reinterpret_cast<const float4*>(e + (size_t)c.y * C_DIM + l * 4);
        float s = zv.x * ev.x + zv.y * ev.y + zv.z * ev.z + zv.w * ev.w;
        #pragma unroll
        for (int off = 32; off; off >>= 1) s += __shfl_xor(s, off, 64);
        if (l == 0) {
            float d = fmaf(-2.0f, s, enorm1[c.y]);   // +1024 shift uniform: order preserved
            u32 ub = __float_as_uint(d);
            ub = (ub & 0x80000000u) ? ~ub : (ub | 0x80000000u);
            u64 key = ((u64)ub << 32) | (u64)c.y;
            atomicMin(packed + c.x, key);
        }
    }
}

// ---------------- finalize indices (clamped: never fault downstream) ----------------
__global__ __launch_bounds__(256) void k_fin(const u64* __restrict__ packed,
                                             int* __restrict__ fidx,
                                             float* __restrict__ out_idx) {
    int n = blockIdx.x * 256 + threadIdx.x;
    if (n >= N_TOT) return;
    u32 kk = (u32)(packed[n] & 0xFFFFFFFFull);
    if (kk > 8191u) kk = 0u;   // safety net: visible wrong answer instead of GPU fault
    fidx[n] = (int)kk;
    out_idx[n] = (float)kk;
}

// ---------------- gather z_q + loss partials ----------------
#define GBLOCKS 2048
__global__ __launch_bounds__(256) void k_gather(const float* __restrict__ z,
                                                const float* __restrict__ e,
                                                const int* __restrict__ fidx,
                                                float* __restrict__ zq,
                                                float* __restrict__ lpart) {
    float s = 0.0f;
    for (int i = blockIdx.x * 256 + threadIdx.x; i < ZQ_SIZE; i += GBLOCKS * 256) {
        int bb = i >> 18;
        int c = (i >> 10) & 255;
        int hw = i & 1023;
        int n = (bb << 10) | hw;
        float q = e[(size_t)fidx[n] * C_DIM + c];
        float zv = z[i];
        zq[i] = q;
        float d = q - zv;
        s = fmaf(d, d, s);
    }
    #pragma unroll
    for (int off = 32; off; off >>= 1) s += __shfl_xor(s, off, 64);
    __shared__ float wsum[4];
    int lane = threadIdx.x & 63, w = threadIdx.x >> 6;
    if (lane == 0) wsum[w] = s;
    __syncthreads();
    if (threadIdx.x == 0) lpart[blockIdx.x] = wsum[0] + wsum[1] + wsum[2] + wsum[3];
}

__global__ __launch_bounds__(256) void k_loss(const float* __restrict__ lpart,
                                              float* __restrict__ out_loss) {
    float s = 0.0f;
    for (int i = threadIdx.x; i < GBLOCKS; i += 256) s += lpart[i];
    #pragma unroll
    for (int off = 32; off; off >>= 1) s += __shfl_xor(s, off, 64);
    __shared__ float wsum[4];
    int lane = threadIdx.x & 63, w = threadIdx.x >> 6;
    if (lane == 0) wsum[w] = s;
    __syncthreads();
    if (threadIdx.x == 0)
        out_loss[0] = (wsum[0] + wsum[1] + wsum[2] + wsum[3]) * (1.25f / (float)ZQ_SIZE);
}

extern "C" void kernel_launch(void* const* d_in, const int* in_sizes, int n_in,
                              void* d_out, int out_size, void* d_ws, size_t ws_size,
                              hipStream_t stream) {
    const float* z = (const float*)d_in[0];
    const float* e = (const float*)d_in[1];
    float* out = (float*)d_out;
    float* ws = (float*)d_ws;

    float* enorm1 = ws + WS_ENORM;
    u32* cnt = (u32*)(ws + WS_CNT);
    u64* packed = (u64*)(ws + WS_PACKED);
    int* fidx = (int*)(ws + WS_FIDX);
    float* lpart = ws + WS_LPART;
    uint2* list = (uint2*)(ws + WS_LIST);
    float* zt32 = ws + WS_ZT32;
    unsigned short* ztb = (unsigned short*)(ws + WS_ZTB16);
    unsigned short* eb = (unsigned short*)(ws + WS_EB16);

    hipMemsetAsync(cnt, 0, sizeof(u32), stream);
    hipMemsetAsync(packed, 0xFF, (size_t)N_TOT * sizeof(u64), stream);

    k_prep_e<<<dim3(K_DIM / 4), dim3(256), 0, stream>>>(e, eb, enorm1);
    k_prep_z<<<dim3(2048), dim3(256), 0, stream>>>(z, zt32, ztb);
    k_screen<<<dim3(512), dim3(256), 0, stream>>>(ztb, eb, enorm1, cnt, list);
    k_exact<<<dim3(512), dim3(256), 0, stream>>>(zt32, e, enorm1, cnt, list, packed);
    k_fin<<<dim3(64), dim3(256), 0, stream>>>(packed, fidx, out + IDX_OFF);
    k_gather<<<dim3(GBLOCKS), dim3(256), 0, stream>>>(z, e, fidx, out, lpart);
    k_loss<<<dim3(1), dim3(256), 0, stream>>>(lpart, out + LOSS_OFF);
}

// Round 10
// 217.641 us; speedup vs baseline: 1.3212x; 1.2640x over previous
//
#include <hip/hip_runtime.h>

typedef unsigned int u32;
typedef unsigned long long u64;

#define C_DIM 256
#define HW 1024
#define N_TOT 16384
#define K_DIM 8192
#define ZQ_SIZE 4194304
#define LOSS_OFF ZQ_SIZE
#define IDX_OFF (ZQ_SIZE + 1)

#define KRANGE 2048
#define MARGIN 2.0f
#define CAP 524288u
#define LCAP 8192u

// workspace offsets (floats)
#define WS_ENORM 0          // 8192 (stores ||e||^2 + 1024)
#define WS_CNT 8192         // 1 u32
#define WS_PACKED 16384     // 16384 u64 = 32768 f
#define WS_FIDX 49152       // 16384
#define WS_LPART 65536      // 2048
#define WS_LIST 131072      // CAP uint2 = 1048576 f
#define WS_ZT32 1179648     // 4194304
#define WS_ZTB16 5373952    // 2097152
#define WS_EB16 7471104     // 1048576 -> ends 8519680 f = 34.1 MB

typedef __attribute__((ext_vector_type(4))) float f32x4;
typedef __attribute__((ext_vector_type(8))) __bf16 bf16x8;
typedef __attribute__((ext_vector_type(8))) unsigned short u16x8;

__device__ __forceinline__ void gld_lds16(const void* g, void* l) {
    __builtin_amdgcn_global_load_lds(
        (const __attribute__((address_space(1))) u32*)g,
        (__attribute__((address_space(3))) u32*)l, 16, 0, 0);
}

__device__ __forceinline__ unsigned short f2bf(float f) {
    u32 u = __float_as_uint(f);
    u32 r = (u + 0x7FFFu + ((u >> 16) & 1u)) >> 16;   // RNE
    return (unsigned short)r;
}

// ---------------- prep e: bf16 codebook + (||e||^2 + 1024) ----------------
__global__ __launch_bounds__(256) void k_prep_e(const float* __restrict__ e,
                                                unsigned short* __restrict__ eb,
                                                float* __restrict__ enorm1) {
    int w = threadIdx.x >> 6, l = threadIdx.x & 63;
    int row = blockIdx.x * 4 + w;
    const float4 v = *reinterpret_cast<const float4*>(e + (size_t)row * C_DIM + l * 4);
    float s = v.x * v.x + v.y * v.y + v.z * v.z + v.w * v.w;
    #pragma unroll
    for (int off = 32; off; off >>= 1) s += __shfl_xor(s, off, 64);
    if (l == 0) enorm1[row] = s + 1024.0f;
    ushort4 h;
    h.x = f2bf(v.x); h.y = f2bf(v.y); h.z = f2bf(v.z); h.w = f2bf(v.w);
    *reinterpret_cast<ushort4*>(eb + (size_t)row * C_DIM + l * 4) = h;
}

// ---------------- prep z: transpose to [n][c], fp32 + bf16 ----------------
__global__ __launch_bounds__(256) void k_prep_z(const float* __restrict__ z,
                                                float* __restrict__ zt32,
                                                unsigned short* __restrict__ ztb) {
    int bid = blockIdx.x;
    int b = bid >> 7;
    int hwt = (bid >> 3) & 15;
    int ct = bid & 7;
    int t = threadIdx.x;
    __shared__ float tile[32][65];
    #pragma unroll
    for (int p = 0; p < 8; ++p) {
        int cl = p * 4 + (t >> 6), hl = t & 63;
        tile[cl][hl] = z[((size_t)b << 18) + ((size_t)(ct * 32 + cl) << 10) + hwt * 64 + hl];
    }
    __syncthreads();
    int hl = t & 63, cg = t >> 6;
    int n = (b << 10) + hwt * 64 + hl;
    float v[8];
    #pragma unroll
    for (int j = 0; j < 8; ++j) v[j] = tile[cg * 8 + j][hl];
    size_t base = (size_t)n * C_DIM + ct * 32 + cg * 8;
    *reinterpret_cast<float4*>(zt32 + base) = make_float4(v[0], v[1], v[2], v[3]);
    *reinterpret_cast<float4*>(zt32 + base + 4) = make_float4(v[4], v[5], v[6], v[7]);
    u16x8 h;
    #pragma unroll
    for (int j = 0; j < 8; ++j) h[j] = f2bf(v[j]);
    *reinterpret_cast<u16x8*>(ztb + base) = h;
}

// ---------------- 8-wave MFMA screen: A resident, B triple-buffered, counted vmcnt ----------------
__global__ __launch_bounds__(512, 1) void k_screen(const unsigned short* __restrict__ zt,
                                                   const unsigned short* __restrict__ et,
                                                   const float* __restrict__ enorm1,
                                                   u32* __restrict__ cnt,
                                                   uint2* __restrict__ list) {
    // LDS: A 65536 | B 3x16384 = 49152 | enorm 8192 | scratch ~2.3KB
    __shared__ __align__(16) char lds[125952];
    char* Ab = lds;
    char* Bb = lds + 65536;
    float* eldsF = (float*)(lds + 114688);

    int logical = (blockIdx.x & 7) * 64 + (blockIdx.x >> 3);   // bijective, XCD-grouped
    const int ks = logical >> 7;
    const int rowtile = logical & 127;
    const int n0 = rowtile * 128;
    const int kbase = ks * KRANGE;

    const int tid = threadIdx.x;           // 0..511
    const int l = tid & 63, w = tid >> 6;  // 8 waves
    const int wr = w >> 2, wc = w & 3;     // 2 x 4 wave grid (64 rows x 64 k each)
    const int ll = l & 15, lh = l >> 4;

    // ---- stage A once: 128 rows x 256 c bf16 (inverse-swizzled source, linear dest) ----
    #pragma unroll
    for (int j = 0; j < 8; ++j) {
        int Y = (w * 8 + j) * 1024 + l * 16;
        int row = Y >> 9;
        int slot = (Y >> 4) & 31;
        const char* src = (const char*)zt + (((size_t)(n0 + row)) << 9) + ((slot ^ (row & 7)) << 4);
        gld_lds16(src, Ab + (w * 8 + j) * 1024);
    }
    // ---- stage enorm slice (2048 f = 8KB): zero compiler-visible VMEM in the K-loop ----
    {
        const char* src = (const char*)(enorm1 + kbase) + w * 1024 + l * 16;
        gld_lds16(src, lds + 114688 + w * 1024);
    }
    // ---- B stage constants: chunk (it,cs) = 256k x 32c = 16KB; 2 instrs/wave ----
    const char* bsrcJ[2];
    #pragma unroll
    for (int j = 0; j < 2; ++j) {
        int D = (j * 8 + w) * 64 + l;      // 16B-unit index 0..1023 in a chunk
        int rB = D >> 2, cB = D & 3;       // row 0..255, col-chunk 0..3
        bsrcJ[j] = (const char*)et + ((size_t)(kbase + rB) << 9) + ((cB ^ ((rB >> 1) & 3)) << 4);
    }
    const int bdst0 = (0 * 8 + w) * 1024, bdst1 = (1 * 8 + w) * 1024;

    // af addressing (rows 0..127)
    int aoff[4], rxA[4];
    #pragma unroll
    for (int mf = 0; mf < 4; ++mf) {
        int row = wr * 64 + mf * 16 + ll;
        aoff[mf] = row * 512;
        rxA[mf] = row & 7;
    }
    // bfr addressing (B rows 0..255; swizzled read matches staged source permutation)
    int bfrOff[4];
    #pragma unroll
    for (int kf = 0; kf < 4; ++kf) {
        int row = wc * 64 + kf * 16 + ll;
        bfrOff[kf] = row * 64 + ((lh ^ ((row >> 1) & 3)) << 4);
    }

    f32x4 acc[4][4];
    #pragma unroll
    for (int a = 0; a < 4; ++a)
        #pragma unroll
        for (int b = 0; b < 4; ++b) acc[a][b] = (f32x4){0.f, 0.f, 0.f, 0.f};
    float m1[16], m2[16];
    #pragma unroll
    for (int s = 0; s < 16; ++s) { m1[s] = 3.4e38f; m2[s] = 3.4e38f; }

    // ---- prologue: stage t=0 -> buf0, t=1 -> buf1 (chunk t: soff = it*131072 + cs*64) ----
    gld_lds16(bsrcJ[0], Bb + bdst0);
    gld_lds16(bsrcJ[1], Bb + bdst1);
    gld_lds16(bsrcJ[0] + 64, Bb + 16384 + bdst0);
    gld_lds16(bsrcJ[1] + 64, Bb + 16384 + bdst1);
    // drain A+enorm+buf0 (keep buf1 in flight), sync
    asm volatile("s_waitcnt vmcnt(2)" ::: "memory");
    __builtin_amdgcn_s_barrier();
    __builtin_amdgcn_sched_barrier(0);

    int bsel = 0;
    for (int it = 0; it < 8; ++it) {
        #pragma unroll
        for (int cs = 0; cs < 8; ++cs) {
            // ---- stage chunk t+2 into buffer (bsel+2)%3 (issue-early) ----
            const int cs2 = (cs + 2) & 7;
            const int itadd = (cs + 2) >> 3;   // compile-time 0/1
            bool do_stage = (cs < 6) || (it < 7);
            if (do_stage) {
                int ssel = bsel + 2; if (ssel >= 3) ssel -= 3;
                const size_t soff = (size_t)(it + itadd) * 131072 + (size_t)(cs2 * 64);
                gld_lds16(bsrcJ[0] + soff, Bb + ssel * 16384 + bdst0);
                gld_lds16(bsrcJ[1] + soff, Bb + ssel * 16384 + bdst1);
            }
            __builtin_amdgcn_sched_barrier(0);
            // ---- compute from buffer bsel ----
            const char* bufp = Bb + bsel * 16384;
            bf16x8 af[4], bfr[4];
            #pragma unroll
            for (int mf = 0; mf < 4; ++mf)
                af[mf] = *reinterpret_cast<const bf16x8*>(
                    Ab + aoff[mf] + (((cs * 4 + lh) ^ rxA[mf]) << 4));
            #pragma unroll
            for (int kf = 0; kf < 4; ++kf)
                bfr[kf] = *reinterpret_cast<const bf16x8*>(bufp + bfrOff[kf]);
            __builtin_amdgcn_s_setprio(1);
            #pragma unroll
            for (int mf = 0; mf < 4; ++mf)
                #pragma unroll
                for (int kf = 0; kf < 4; ++kf)
                    acc[mf][kf] = __builtin_amdgcn_mfma_f32_16x16x32_bf16(
                        af[mf], bfr[kf], acc[mf][kf], 0, 0, 0);
            __builtin_amdgcn_s_setprio(0);

            if (cs == 7) {
                // epilogue: packed (d,k) top-2 update; d = en' - 2*dot (enorm from LDS)
                #pragma unroll
                for (int kf = 0; kf < 4; ++kf) {
                    float en = eldsF[it * 256 + wc * 64 + kf * 16 + ll];
                    const u32 kcol = (u32)(kbase + it * 256 + wc * 64 + kf * 16 + ll);
                    #pragma unroll
                    for (int mf = 0; mf < 4; ++mf) {
                        #pragma unroll
                        for (int r = 0; r < 4; ++r) {
                            float d = fmaf(-2.0f, acc[mf][kf][r], en);
                            float df = __uint_as_float((__float_as_uint(d) & 0xFFFFE000u) | kcol);
                            const int s2 = mf * 4 + r;
                            float t = fmaxf(m1[s2], df);
                            m2[s2] = fminf(m2[s2], t);
                            m1[s2] = fminf(m1[s2], df);
                            acc[mf][kf][r] = 0.0f;
                        }
                    }
                }
            }
            // ---- end-of-step: counted drain (next buffer ready), raw barrier ----
            if (!(it == 7 && cs == 7)) {
                if (cs == 6) {
                    if (it == 7) { asm volatile("s_waitcnt vmcnt(0)" ::: "memory"); }
                    else         { asm volatile("s_waitcnt vmcnt(2)" ::: "memory"); }
                } else {
                    asm volatile("s_waitcnt vmcnt(2)" ::: "memory");
                }
                __builtin_amdgcn_s_barrier();
                __builtin_amdgcn_sched_barrier(0);
            }
            bsel = bsel + 1; if (bsel >= 3) bsel -= 3;
        }
    }

    // ---- row-split min via butterfly on a COPY (per-thread m1/m2 preserved) ----
    float rowm[16];
    #pragma unroll
    for (int s = 0; s < 16; ++s) rowm[s] = m1[s];
    #pragma unroll
    for (int m = 1; m <= 8; m <<= 1)
        #pragma unroll
        for (int s = 0; s < 16; ++s)
            rowm[s] = fminf(rowm[s], __shfl_xor(rowm[s], m, 64));

    // LDS scratch
    float* LDSrm = (float*)(lds + 122880);   // [128][4]
    float* LDSrmF = (float*)(lds + 124928);  // [128]
    u32* ccnt = (u32*)(lds + 125440);
    u32* gbase = (u32*)(lds + 125444);
    uint2* cbuf = (uint2*)Ab;                // 8192 entries

    if (ll == 0) {
        #pragma unroll
        for (int s = 0; s < 16; ++s) {
            int row_local = wr * 64 + (s >> 2) * 16 + lh * 4 + (s & 3);
            LDSrm[row_local * 4 + wc] = rowm[s];
        }
    }
    if (tid == 0) *ccnt = 0;
    __syncthreads();
    if (tid < 128)
        LDSrmF[tid] = fminf(fminf(LDSrm[tid * 4], LDSrm[tid * 4 + 1]),
                            fminf(LDSrm[tid * 4 + 2], LDSrm[tid * 4 + 3]));
    __syncthreads();

    // ---- emission (per-thread bests; block-compacted) ----
    #pragma unroll
    for (int s = 0; s < 16; ++s) {
        int row_local = wr * 64 + (s >> 2) * 16 + lh * 4 + (s & 3);
        float rm = __uint_as_float(__float_as_uint(LDSrmF[row_local]) & 0xFFFFE000u);
        float d1 = __uint_as_float(__float_as_uint(m1[s]) & 0xFFFFE000u);
        if (d1 <= rm + MARGIN) {
            u32 pos = atomicAdd(ccnt, 1u);
            uint2 ent = make_uint2((u32)(n0 + row_local), __float_as_uint(m1[s]) & 8191u);
            if (pos < LCAP) cbuf[pos] = ent;
            else { u32 gp = atomicAdd(cnt, 1u); if (gp < CAP) list[gp] = ent; }
        }
        float d2 = __uint_as_float(__float_as_uint(m2[s]) & 0xFFFFE000u);
        if (d2 <= rm + MARGIN) {
            // rare: a 3rd candidate may hide in this thread-slot's 32-k subset -> emit all
            for (int it2 = 0; it2 < 8; ++it2) {
                #pragma unroll
                for (int kf = 0; kf < 4; ++kf) {
                    u32 k = (u32)(kbase + it2 * 256 + wc * 64 + kf * 16 + ll);
                    u32 pos = atomicAdd(ccnt, 1u);
                    uint2 ent = make_uint2((u32)(n0 + row_local), k);
                    if (pos < LCAP) cbuf[pos] = ent;
                    else { u32 gp = atomicAdd(cnt, 1u); if (gp < CAP) list[gp] = ent; }
                }
            }
        }
    }
    __syncthreads();
    if (tid == 0) {
        u32 total = *ccnt; if (total > LCAP) total = LCAP;
        *gbase = atomicAdd(cnt, total);
    }
    __syncthreads();
    u32 total = *ccnt; if (total > LCAP) total = LCAP;
    u32 gb = *gbase;
    for (u32 i = tid; i < total; i += 512) {
        u32 gp = gb + i;
        if (gp < CAP) list[gp] = cbuf[i];
    }
}

// ---------------- exact fp32 recheck of candidates ----------------
__global__ __launch_bounds__(256) void k_exact(const float* __restrict__ zt32,
                                               const float* __restrict__ e,
                                               const float* __restrict__ enorm1,
                                               const u32* __restrict__ cnt,
                                               const uint2* __restrict__ list,
                                               u64* __restrict__ packed) {
    const int nw = gridDim.x * 4;
    const int wid = blockIdx.x * 4 + (threadIdx.x >> 6);
    const int l = threadIdx.x & 63;
    u32 total = *cnt;
    if (total > CAP) total = CAP;
    for (u32 i = wid; i < total; i += nw) {
        uint2 c = list[i];
        const float4 zv = *reinterpret_cast<const float4*>(zt32 + (size_t)c.x * C_DIM + l * 4);
        const float4 ev = *reinterpret_cast<const float4*>(e + (size_t)c.y * C_DIM + l * 4);
        float s = zv.x * ev.x + zv.y * ev.y + zv.z * ev.z + zv.w * ev.w;
        #pragma unroll
        for (int off = 32; off; off >>= 1) s += __shfl_xor(s, off, 64);
        if (l == 0) {
            float d = fmaf(-2.0f, s, enorm1[c.y]);   // +1024 shift uniform: order preserved
            u32 ub = __float_as_uint(d);
            ub = (ub & 0x80000000u) ? ~ub : (ub | 0x80000000u);
            u64 key = ((u64)ub << 32) | (u64)c.y;
            atomicMin(packed + c.x, key);
        }
    }
}

// ---------------- finalize indices (clamped: never fault downstream) ----------------
__global__ __launch_bounds__(256) void k_fin(const u64* __restrict__ packed,
                                             int* __restrict__ fidx,
                                             float* __restrict__ out_idx) {
    int n = blockIdx.x * 256 + threadIdx.x;
    if (n >= N_TOT) return;
    u32 kk = (u32)(packed[n] & 0xFFFFFFFFull);
    if (kk > 8191u) kk = 0u;   // safety net: visible wrong answer instead of GPU fault
    fidx[n] = (int)kk;
    out_idx[n] = (float)kk;
}

// ---------------- gather z_q + loss partials ----------------
#define GBLOCKS 2048
__global__ __launch_bounds__(256) void k_gather(const float* __restrict__ z,
                                                const float* __restrict__ e,
                                                const int* __restrict__ fidx,
                                                float* __restrict__ zq,
                                                float* __restrict__ lpart) {
    float s = 0.0f;
    for (int i = blockIdx.x * 256 + threadIdx.x; i < ZQ_SIZE; i += GBLOCKS * 256) {
        int bb = i >> 18;
        int c = (i >> 10) & 255;
        int hw = i & 1023;
        int n = (bb << 10) | hw;
        float q = e[(size_t)fidx[n] * C_DIM + c];
        float zv = z[i];
        zq[i] = q;
        float d = q - zv;
        s = fmaf(d, d, s);
    }
    #pragma unroll
    for (int off = 32; off; off >>= 1) s += __shfl_xor(s, off, 64);
    __shared__ float wsum[4];
    int lane = threadIdx.x & 63, w = threadIdx.x >> 6;
    if (lane == 0) wsum[w] = s;
    __syncthreads();
    if (threadIdx.x == 0) lpart[blockIdx.x] = wsum[0] + wsum[1] + wsum[2] + wsum[3];
}

__global__ __launch_bounds__(256) void k_loss(const float* __restrict__ lpart,
                                              float* __restrict__ out_loss) {
    float s = 0.0f;
    for (int i = threadIdx.x; i < GBLOCKS; i += 256) s += lpart[i];
    #pragma unroll
    for (int off = 32; off; off >>= 1) s += __shfl_xor(s, off, 64);
    __shared__ float wsum[4];
    int lane = threadIdx.x & 63, w = threadIdx.x >> 6;
    if (lane == 0) wsum[w] = s;
    __syncthreads();
    if (threadIdx.x == 0)
        out_loss[0] = (wsum[0] + wsum[1] + wsum[2] + wsum[3]) * (1.25f / (float)ZQ_SIZE);
}

extern "C" void kernel_launch(void* const* d_in, const int* in_sizes, int n_in,
                              void* d_out, int out_size, void* d_ws, size_t ws_size,
                              hipStream_t stream) {
    const float* z = (const float*)d_in[0];
    const float* e = (const float*)d_in[1];
    float* out = (float*)d_out;
    float* ws = (float*)d_ws;

    float* enorm1 = ws + WS_ENORM;
    u32* cnt = (u32*)(ws + WS_CNT);
    u64* packed = (u64*)(ws + WS_PACKED);
    int* fidx = (int*)(ws + WS_FIDX);
    float* lpart = ws + WS_LPART;
    uint2* list = (uint2*)(ws + WS_LIST);
    float* zt32 = ws + WS_ZT32;
    unsigned short* ztb = (unsigned short*)(ws + WS_ZTB16);
    unsigned short* eb = (unsigned short*)(ws + WS_EB16);

    hipMemsetAsync(cnt, 0, sizeof(u32), stream);
    hipMemsetAsync(packed, 0xFF, (size_t)N_TOT * sizeof(u64), stream);

    k_prep_e<<<dim3(K_DIM / 4), dim3(256), 0, stream>>>(e, eb, enorm1);
    k_prep_z<<<dim3(2048), dim3(256), 0, stream>>>(z, zt32, ztb);
    k_screen<<<dim3(512), dim3(512), 0, stream>>>(ztb, eb, enorm1, cnt, list);
    k_exact<<<dim3(1024), dim3(256), 0, stream>>>(zt32, e, enorm1, cnt, list, packed);
    k_fin<<<dim3(64), dim3(256), 0, stream>>>(packed, fidx, out + IDX_OFF);
    k_gather<<<dim3(GBLOCKS), dim3(256), 0, stream>>>(z, e, fidx, out, lpart);
    k_loss<<<dim3(1), dim3(256), 0, stream>>>(lpart, out + LOSS_OFF);
}